// Round 1
// baseline (233.227 us; speedup 1.0000x reference)
//
#include <hip/hip_runtime.h>

#define NROWS 16384
#define NG 100
#define NC 10
#define NH 32
#define NS 10
#define GPC 10
#define SLOPE 0.2f
#define BN_EPS 1e-5f

#define EPAD 36            // padded LDS row stride (floats): x=0/1/2 rows hit distinct bank groups, 16B aligned
#define ROWS_PER_BLOCK 64
#define BLOCK_A 256        // 64 rows * 4 h-quads

__global__ __launch_bounds__(BLOCK_A) void gga_main(
    const int* __restrict__ x, const float* __restrict__ emb,
    const float* __restrict__ gene_att, const float* __restrict__ chrom_att,
    const float* __restrict__ W, const float* __restrict__ b,
    float* __restrict__ y, float* __restrict__ sums)
{
    __shared__ float embL[300 * EPAD];   // 43.2 KB
    __shared__ float attvalL[300];       // dot(gene_att[g/10], emb[g,x,:]) for all (g,x)
    __shared__ float WL[NH * NS];
    __shared__ float bL[NS];

    const int t = threadIdx.x;

    // stage emb: 9600 floats = 2400 float4, coalesced
    for (int i = t; i < 2400; i += BLOCK_A) {
        float4 v = reinterpret_cast<const float4*>(emb)[i];
        int f = i << 2;
        int row = f >> 5;   // g*3 + x
        int h = f & 31;
        *reinterpret_cast<float4*>(&embL[row * EPAD + h]) = v;
    }
    for (int i = t; i < NH * NS; i += BLOCK_A) WL[i] = W[i];
    if (t < NS) bL[t] = b[t];
    __syncthreads();

    // attval table: 300 dot products of length 32
    for (int r = t; r < 300; r += BLOCK_A) {
        int g = r / 3;
        const float* ga = gene_att + (g / GPC) * NH;
        const float* e = &embL[r * EPAD];
        float s = 0.f;
#pragma unroll
        for (int k = 0; k < NH; ++k) s = fmaf(ga[k], e[k], s);
        attvalL[r] = s;
    }
    __syncthreads();

    const int lr = t >> 2;          // local row 0..63
    const int q = t & 3;            // h-quad: owns components 8q..8q+7
    const int n = blockIdx.x * ROWS_PER_BLOCK + lr;

    const float4 ca0 = reinterpret_cast<const float4*>(chrom_att)[q * 2 + 0];
    const float4 ca1 = reinterpret_cast<const float4*>(chrom_att)[q * 2 + 1];

    // load x row (100 trits), pack 16 trits per u32 (all indices compile-time)
    unsigned pk[7] = {0u,0u,0u,0u,0u,0u,0u};
    const int4* xr = reinterpret_cast<const int4*>(x + n * NG);
#pragma unroll
    for (int i = 0; i < 25; ++i) {
        int4 v = xr[i];
        const int g0 = i * 4;
        pk[(g0 + 0) >> 4] |= ((unsigned)v.x & 3u) << (((g0 + 0) & 15) * 2);
        pk[(g0 + 1) >> 4] |= ((unsigned)v.y & 3u) << (((g0 + 1) & 15) * 2);
        pk[(g0 + 2) >> 4] |= ((unsigned)v.z & 3u) << (((g0 + 2) & 15) * 2);
        pk[(g0 + 3) >> 4] |= ((unsigned)v.w & 3u) << (((g0 + 3) & 15) * 2);
    }

    float4 num0 = {0,0,0,0}, num1 = {0,0,0,0};
    float den = 0.f;

#pragma unroll
    for (int c = 0; c < NC; ++c) {
        // gene attention weights for this chromosome's 10 genes
        float a[GPC];
        float suma = 0.f;
#pragma unroll
        for (int gp = 0; gp < GPC; ++gp) {
            const int g = c * GPC + gp;
            const unsigned xg = (pk[g >> 4] >> ((g & 15) * 2)) & 3u;
            const float att = attvalL[g * 3 + (int)xg];
            const float l = att > 0.f ? att : SLOPE * att;
            const float e = (att != 0.f) ? __expf(l) : 0.f;   // mask = (att != 0)
            a[gp] = e;
            suma += e;
        }
        const float inv = 1.f / fmaxf(suma, 1e-10f);

        // chrom vector (this quad's 8 components)
        float4 ch0 = {0,0,0,0}, ch1 = {0,0,0,0};
#pragma unroll
        for (int gp = 0; gp < GPC; ++gp) {
            const int g = c * GPC + gp;
            const unsigned xg = (pk[g >> 4] >> ((g & 15) * 2)) & 3u;
            const float* hp = &embL[(g * 3 + (int)xg) * EPAD + q * 8];
            const float4 h0 = *reinterpret_cast<const float4*>(hp);
            const float4 h1 = *reinterpret_cast<const float4*>(hp + 4);
            const float w = a[gp];
            ch0.x = fmaf(w, h0.x, ch0.x); ch0.y = fmaf(w, h0.y, ch0.y);
            ch0.z = fmaf(w, h0.z, ch0.z); ch0.w = fmaf(w, h0.w, ch0.w);
            ch1.x = fmaf(w, h1.x, ch1.x); ch1.y = fmaf(w, h1.y, ch1.y);
            ch1.z = fmaf(w, h1.z, ch1.z); ch1.w = fmaf(w, h1.w, ch1.w);
        }
        // normalize + ReLU
        ch0.x = fmaxf(ch0.x * inv, 0.f); ch0.y = fmaxf(ch0.y * inv, 0.f);
        ch0.z = fmaxf(ch0.z * inv, 0.f); ch0.w = fmaxf(ch0.w * inv, 0.f);
        ch1.x = fmaxf(ch1.x * inv, 0.f); ch1.y = fmaxf(ch1.y * inv, 0.f);
        ch1.z = fmaxf(ch1.z * inv, 0.f); ch1.w = fmaxf(ch1.w * inv, 0.f);

        // chromosome attention logit: partial dot + quad reduce
        float pc = ch0.x*ca0.x + ch0.y*ca0.y + ch0.z*ca0.z + ch0.w*ca0.w
                 + ch1.x*ca1.x + ch1.y*ca1.y + ch1.z*ca1.z + ch1.w*ca1.w;
        pc += __shfl_xor(pc, 1);
        pc += __shfl_xor(pc, 2);
        const float lc = pc > 0.f ? pc : SLOPE * pc;
        const float ec = __expf(lc);

        num0.x = fmaf(ec, ch0.x, num0.x); num0.y = fmaf(ec, ch0.y, num0.y);
        num0.z = fmaf(ec, ch0.z, num0.z); num0.w = fmaf(ec, ch0.w, num0.w);
        num1.x = fmaf(ec, ch1.x, num1.x); num1.y = fmaf(ec, ch1.y, num1.y);
        num1.z = fmaf(ec, ch1.z, num1.z); num1.w = fmaf(ec, ch1.w, num1.w);
        den += ec;
    }

    const float invd = 1.f / den;
    float gv[8];
    gv[0] = fmaxf(num0.x * invd, 0.f); gv[1] = fmaxf(num0.y * invd, 0.f);
    gv[2] = fmaxf(num0.z * invd, 0.f); gv[3] = fmaxf(num0.w * invd, 0.f);
    gv[4] = fmaxf(num1.x * invd, 0.f); gv[5] = fmaxf(num1.y * invd, 0.f);
    gv[6] = fmaxf(num1.z * invd, 0.f); gv[7] = fmaxf(num1.w * invd, 0.f);

    float ys[NS];
#pragma unroll
    for (int s = 0; s < NS; ++s) {
        float p = 0.f;
#pragma unroll
        for (int j = 0; j < 8; ++j)
            p = fmaf(gv[j], WL[(q * 8 + j) * NS + s], p);
        p += __shfl_xor(p, 1);
        p += __shfl_xor(p, 2);
        ys[s] = p + bL[s];
    }

    if (q == 0) {
#pragma unroll
        for (int s = 0; s < NS; ++s) y[n * NS + s] = ys[s];
    }

    // BN partial sums: each row appears 4x in the wave -> scale by 0.25
#pragma unroll
    for (int s = 0; s < NS; ++s) {
        float v = ys[s];
        float v2 = v * v;
#pragma unroll
        for (int off = 32; off >= 1; off >>= 1) {
            v  += __shfl_down(v, off);
            v2 += __shfl_down(v2, off);
        }
        if ((t & 63) == 0) {
            atomicAdd(&sums[s],      v * 0.25f);
            atomicAdd(&sums[NS + s], v2 * 0.25f);
        }
    }
}

__global__ __launch_bounds__(256) void gga_bn(
    float* __restrict__ out, const float* __restrict__ sums,
    const float* __restrict__ gamma, const float* __restrict__ beta)
{
    const int idx = blockIdx.x * 256 + threadIdx.x;
    const int s = idx % NS;
    const float mu = sums[s] * (1.f / NROWS);
    float var = sums[NS + s] * (1.f / NROWS) - mu * mu;
    var = fmaxf(var, 0.f);
    const float r = rsqrtf(var + BN_EPS);
    const float sc = gamma[s] * r;
    const float sh = beta[s] - mu * sc;
    out[idx] = out[idx] * sc + sh;
}

extern "C" void kernel_launch(void* const* d_in, const int* in_sizes, int n_in,
                              void* d_out, int out_size, void* d_ws, size_t ws_size,
                              hipStream_t stream) {
    const int*   x         = (const int*)d_in[0];
    const float* emb       = (const float*)d_in[1];
    const float* gene_att  = (const float*)d_in[2];
    const float* chrom_att = (const float*)d_in[3];
    const float* W         = (const float*)d_in[4];
    const float* b         = (const float*)d_in[5];
    const float* bn_gamma  = (const float*)d_in[6];
    const float* bn_beta   = (const float*)d_in[7];

    float* y    = (float*)d_out;      // pre-BN y lives in d_out; normalized in place
    float* sums = (float*)d_ws;       // 20 floats: sum[10], sumsq[10]

    hipMemsetAsync(sums, 0, 2 * NS * sizeof(float), stream);
    gga_main<<<NROWS / ROWS_PER_BLOCK, BLOCK_A, 0, stream>>>(
        x, emb, gene_att, chrom_att, W, b, y, sums);
    gga_bn<<<(NROWS * NS) / 256, 256, 0, stream>>>(y, sums, bn_gamma, bn_beta);
}

// Round 2
// 29.759 us; speedup vs baseline: 7.8371x; 7.8371x over previous
//
#include <hip/hip_runtime.h>

#define NROWS 16384
#define NG 100
#define NC 10
#define NH 32
#define NS 10
#define GPC 10
#define SLOPE 0.2f
#define BN_EPS 1e-5f

#define EPAD 36            // padded LDS row stride (floats); stride mod 32 = 4 spreads rows across banks
#define RPB 32             // rows per block
#define BLOCK_A 256        // 32 rows * 8 lanes/row

__global__ __launch_bounds__(BLOCK_A, 2) void gga_main(
    const int* __restrict__ x, const float* __restrict__ emb,
    const float* __restrict__ gene_att, const float* __restrict__ chrom_att,
    const float* __restrict__ W, const float* __restrict__ b,
    float* __restrict__ y, float* __restrict__ sums)
{
    __shared__ float embL[300 * EPAD];   // 43.2 KB
    __shared__ float eL[300];            // exp(leaky(att)) * mask, per (g,x)
    __shared__ float WT[NS][NH];         // W transposed: WT[s][h]
    __shared__ float bL[NS];
    __shared__ float sAcc[2 * NS];

    const int t = threadIdx.x;

    // stage emb: 9600 floats = 2400 float4, coalesced
    for (int i = t; i < 2400; i += BLOCK_A) {
        float4 v = reinterpret_cast<const float4*>(emb)[i];
        int f = i << 2;
        int row = f >> 5;   // g*3 + x
        int h = f & 31;
        *reinterpret_cast<float4*>(&embL[row * EPAD + h]) = v;
    }
    for (int i = t; i < NH * NS; i += BLOCK_A) {
        int hh = i / NS, ss = i % NS;
        WT[ss][hh] = W[i];
    }
    if (t < NS) bL[t] = b[t];
    if (t < 2 * NS) sAcc[t] = 0.f;
    __syncthreads();

    // e-table: 300 dot-32 + leaky + exp + mask, once per block
    for (int r = t; r < 300; r += BLOCK_A) {
        int g = r / 3;
        const float* ga = gene_att + (g / GPC) * NH;
        const float* e = &embL[r * EPAD];
        float s = 0.f;
#pragma unroll
        for (int k = 0; k < NH; ++k) s = fmaf(ga[k], e[k], s);
        const float l = s > 0.f ? s : SLOPE * s;
        eL[r] = (s != 0.f) ? __expf(l) : 0.f;
    }
    __syncthreads();

    const int lr = t >> 3;          // local row 0..31
    const int o = t & 7;            // owns h components 4o..4o+3
    const int n = blockIdx.x * RPB + lr;

    const float4 ca = reinterpret_cast<const float4*>(chrom_att)[o];

    // load x row (100 trits), pack 16 trits per u32 (all indices compile-time)
    unsigned pk[7] = {0u,0u,0u,0u,0u,0u,0u};
    const int4* xr = reinterpret_cast<const int4*>(x + n * NG);
#pragma unroll
    for (int i = 0; i < 25; ++i) {
        int4 v = xr[i];
        const int g0 = i * 4;
        pk[(g0 + 0) >> 4] |= ((unsigned)v.x & 3u) << (((g0 + 0) & 15) * 2);
        pk[(g0 + 1) >> 4] |= ((unsigned)v.y & 3u) << (((g0 + 1) & 15) * 2);
        pk[(g0 + 2) >> 4] |= ((unsigned)v.z & 3u) << (((g0 + 2) & 15) * 2);
        pk[(g0 + 3) >> 4] |= ((unsigned)v.w & 3u) << (((g0 + 3) & 15) * 2);
    }

    float4 num = {0,0,0,0};
    float den = 0.f;

#pragma unroll
    for (int c = 0; c < NC; ++c) {
        // batch all 20 independent gathers for this chromosome
        float e[GPC];
        float4 hv[GPC];
#pragma unroll
        for (int gp = 0; gp < GPC; ++gp) {
            const int g = c * GPC + gp;
            const unsigned xg = (pk[g >> 4] >> ((g & 15) * 2)) & 3u;
            const int row = g * 3 + (int)xg;
            e[gp] = eL[row];
            hv[gp] = *reinterpret_cast<const float4*>(&embL[row * EPAD + o * 4]);
        }
        float suma = 0.f;
#pragma unroll
        for (int gp = 0; gp < GPC; ++gp) suma += e[gp];
        const float inv = 1.f / fmaxf(suma, 1e-10f);   // runs parallel to fma tree below

        float4 ch = {0,0,0,0};
#pragma unroll
        for (int gp = 0; gp < GPC; ++gp) {
            ch.x = fmaf(e[gp], hv[gp].x, ch.x);
            ch.y = fmaf(e[gp], hv[gp].y, ch.y);
            ch.z = fmaf(e[gp], hv[gp].z, ch.z);
            ch.w = fmaf(e[gp], hv[gp].w, ch.w);
        }
        // ReLU on raw sum; inv (>0) folds in later
        ch.x = fmaxf(ch.x, 0.f); ch.y = fmaxf(ch.y, 0.f);
        ch.z = fmaxf(ch.z, 0.f); ch.w = fmaxf(ch.w, 0.f);

        float pc = ch.x*ca.x + ch.y*ca.y + ch.z*ca.z + ch.w*ca.w;
        pc += __shfl_xor(pc, 1);
        pc += __shfl_xor(pc, 2);
        pc += __shfl_xor(pc, 4);
        pc *= inv;                                      // = catt[n][c]
        const float lc = pc > 0.f ? pc : SLOPE * pc;
        const float ec = __expf(lc);
        const float w = ec * inv;

        num.x = fmaf(w, ch.x, num.x); num.y = fmaf(w, ch.y, num.y);
        num.z = fmaf(w, ch.z, num.z); num.w = fmaf(w, ch.w, num.w);
        den += ec;
    }

    const float invd = 1.f / den;
    const float g0 = fmaxf(num.x * invd, 0.f);
    const float g1 = fmaxf(num.y * invd, 0.f);
    const float g2 = fmaxf(num.z * invd, 0.f);
    const float g3 = fmaxf(num.w * invd, 0.f);

    float ys[NS];
#pragma unroll
    for (int s = 0; s < NS; ++s) {
        const float4 wv = *reinterpret_cast<const float4*>(&WT[s][o * 4]);
        float p = g0*wv.x + g1*wv.y + g2*wv.z + g3*wv.w;
        p += __shfl_xor(p, 1);
        p += __shfl_xor(p, 2);
        p += __shfl_xor(p, 4);
        ys[s] = p + bL[s];
    }

    if (o == 0) {
#pragma unroll
        for (int s = 0; s < NS; ++s) y[n * NS + s] = ys[s];
    }

    // BN partials: sum over the wave's 8 rows (same-o lanes only -> each row once)
#pragma unroll
    for (int s = 0; s < NS; ++s) {
        float v = ys[s];
        float v2 = v * v;
        v += __shfl_xor(v, 8);  v2 += __shfl_xor(v2, 8);
        v += __shfl_xor(v, 16); v2 += __shfl_xor(v2, 16);
        v += __shfl_xor(v, 32); v2 += __shfl_xor(v2, 32);
        if ((t & 63) == 0) {
            atomicAdd(&sAcc[s],      v);
            atomicAdd(&sAcc[NS + s], v2);
        }
    }
    __syncthreads();
    if (t < 2 * NS) atomicAdd(&sums[t], sAcc[t]);
}

__global__ __launch_bounds__(256) void gga_bn(
    float* __restrict__ out, const float* __restrict__ sums,
    const float* __restrict__ gamma, const float* __restrict__ beta)
{
    const int idx = blockIdx.x * 256 + threadIdx.x;
    const int s = idx % NS;
    const float mu = sums[s] * (1.f / NROWS);
    float var = sums[NS + s] * (1.f / NROWS) - mu * mu;
    var = fmaxf(var, 0.f);
    const float r = rsqrtf(var + BN_EPS);
    const float sc = gamma[s] * r;
    const float sh = beta[s] - mu * sc;
    out[idx] = out[idx] * sc + sh;
}

extern "C" void kernel_launch(void* const* d_in, const int* in_sizes, int n_in,
                              void* d_out, int out_size, void* d_ws, size_t ws_size,
                              hipStream_t stream) {
    const int*   x         = (const int*)d_in[0];
    const float* emb       = (const float*)d_in[1];
    const float* gene_att  = (const float*)d_in[2];
    const float* chrom_att = (const float*)d_in[3];
    const float* W         = (const float*)d_in[4];
    const float* b         = (const float*)d_in[5];
    const float* bn_gamma  = (const float*)d_in[6];
    const float* bn_beta   = (const float*)d_in[7];

    float* y    = (float*)d_out;      // pre-BN y in d_out; normalized in place
    float* sums = (float*)d_ws;       // 20 floats: sum[10], sumsq[10]

    hipMemsetAsync(sums, 0, 2 * NS * sizeof(float), stream);
    gga_main<<<NROWS / RPB, BLOCK_A, 0, stream>>>(
        x, emb, gene_att, chrom_att, W, b, y, sums);
    gga_bn<<<(NROWS * NS) / 256, 256, 0, stream>>>(y, sums, bn_gamma, bn_beta);
}